// Round 2
// baseline (114.119 us; speedup 1.0000x reference)
//
#include <hip/hip_runtime.h>
#include <hip/hip_fp16.h>
#include <stdint.h>

#define D0 1024
#define D1 8192
#define D2 8192
#define D3 10240
#define NGATES (D1 + D2 + D3)   // 26624
#define B_ROWS 4096

// LDS layout (bytes). h1 first so stage-C gather offsets need no base add
// (layer-2 byte offsets ia*8 <= 65528 fit the u16 packed index directly).
#define SMEM_H1    0
#define SMEM_H2    65536
#define SMEM_XB    131072
#define SMEM_CSUM  139264
#define SMEM_BYTES (139264 + 160)

// Pre-pass: per gate, softmax(w[16]) @ OP_COEF -> 4 coefs stored as
// half2-DUPLICATED uint4 (c0c0,c1c1,c2c2,c3c3) so the fused kernel needs no
// unpack VALU; gather indices stored as PRE-SCALED byte offsets
// (ia*8)|(ib*8)<<16. Row-invariant -> computed once per launch.
__global__ __launch_bounds__(64) void prep_kernel(
    const float* __restrict__ w1, const float* __restrict__ w2,
    const float* __restrict__ w3,
    const int* __restrict__ ia1, const int* __restrict__ ib1,
    const int* __restrict__ ia2, const int* __restrict__ ib2,
    const int* __restrict__ ia3, const int* __restrict__ ib3,
    uint4* __restrict__ coefb, uint32_t* __restrict__ idxp) {
    int G = blockIdx.x * 64 + threadIdx.x;  // grid is exactly NGATES/64
    const float* w;
    int ia, ib;
    if (G < D1) {
        w = w1 + (size_t)G * 16; ia = ia1[G]; ib = ib1[G];
    } else if (G < D1 + D2) {
        int g = G - D1;
        w = w2 + (size_t)g * 16; ia = ia2[g]; ib = ib2[g];
    } else {
        int g = G - D1 - D2;
        w = w3 + (size_t)g * 16; ia = ia3[g]; ib = ib3[g];
    }
    // 64 B row, 16 B aligned -> 4x dwordx4 loads.
    const float4* wv = (const float4*)w;
    float4 q0 = wv[0], q1 = wv[1], q2 = wv[2], q3 = wv[3];
    float wa[16] = {q0.x, q0.y, q0.z, q0.w, q1.x, q1.y, q1.z, q1.w,
                    q2.x, q2.y, q2.z, q2.w, q3.x, q3.y, q3.z, q3.w};
    float m = wa[0];
#pragma unroll
    for (int i = 1; i < 16; ++i) m = fmaxf(m, wa[i]);
    float e[16], s = 0.f;
#pragma unroll
    for (int i = 0; i < 16; ++i) { e[i] = __expf(wa[i] - m); s += e[i]; }
    float inv = 1.f / s;
    static constexpr float OPC[16][4] = {
        {0.f, 0.f, 0.f, 0.f}, {0.f, 0.f, 0.f, 1.f}, {0.f, 1.f, 0.f, -1.f}, {0.f, 1.f, 0.f, 0.f},
        {0.f, 0.f, 1.f, -1.f}, {0.f, 0.f, 1.f, 0.f}, {0.f, 1.f, 1.f, -2.f}, {0.f, 1.f, 1.f, -1.f},
        {1.f, -1.f, -1.f, 1.f}, {1.f, -1.f, -1.f, 2.f}, {1.f, 0.f, -1.f, 0.f}, {1.f, 0.f, -1.f, 1.f},
        {1.f, -1.f, 0.f, 0.f}, {1.f, -1.f, 0.f, 1.f}, {1.f, 0.f, 0.f, -1.f}, {1.f, 0.f, 0.f, 0.f}};
    float c0 = 0.f, c1 = 0.f, c2 = 0.f, c3 = 0.f;
#pragma unroll
    for (int i = 0; i < 16; ++i) {  // multiplies by 0/±1/±2 fold at compile time
        float p = e[i] * inv;
        c0 += p * OPC[i][0];
        c1 += p * OPC[i][1];
        c2 += p * OPC[i][2];
        c3 += p * OPC[i][3];
    }
    uint4 cv;
    cv.x = __builtin_bit_cast(uint32_t, __floats2half2_rn(c0, c0));
    cv.y = __builtin_bit_cast(uint32_t, __floats2half2_rn(c1, c1));
    cv.z = __builtin_bit_cast(uint32_t, __floats2half2_rn(c2, c2));
    cv.w = __builtin_bit_cast(uint32_t, __floats2half2_rn(c3, c3));
    coefb[G] = cv;
    idxp[G] = (uint32_t)(ia << 3) | ((uint32_t)(ib << 3) << 16);
}

// One gate for 4 rows (2x half2), coefs pre-broadcast.
// h = (c0 + c2*b) + a*(c1 + c3*b): 6 v_pk_fma_f16, zero unpack ops.
__device__ __forceinline__ uint2 gate4(uint2 av, uint2 bv, uint4 cf) {
    __half2 a01 = __builtin_bit_cast(__half2, av.x);
    __half2 a23 = __builtin_bit_cast(__half2, av.y);
    __half2 b01 = __builtin_bit_cast(__half2, bv.x);
    __half2 b23 = __builtin_bit_cast(__half2, bv.y);
    __half2 c0 = __builtin_bit_cast(__half2, cf.x);
    __half2 c1 = __builtin_bit_cast(__half2, cf.y);
    __half2 c2 = __builtin_bit_cast(__half2, cf.z);
    __half2 c3 = __builtin_bit_cast(__half2, cf.w);
    __half2 h01 = __hfma2(a01, __hfma2(b01, c3, c1), __hfma2(b01, c2, c0));
    __half2 h23 = __hfma2(a23, __hfma2(b23, c3, c1), __hfma2(b23, c2, c0));
    uint2 r;
    r.x = __builtin_bit_cast(uint32_t, h01);
    r.y = __builtin_bit_cast(uint32_t, h23);
    return r;
}

// Fused 3-layer + group-sum. One block = 4 batch rows; activations in LDS,
// row-interleaved [gate][4 rows] fp16 so one ds_read_b64 feeds 4 rows.
// Metadata for each stage is register-prefetched BEFORE the preceding barrier
// so the ~300-cycle L2 latency drains during the barrier wait.
__global__ __launch_bounds__(1024) void fused_kernel(
    const float* __restrict__ x, const uint4* __restrict__ coefb,
    const uint32_t* __restrict__ idxp, float* __restrict__ out) {
    extern __shared__ char smem[];
    char* sm = smem;
    uint2* h1 = (uint2*)(sm + SMEM_H1);
    uint2* h2 = (uint2*)(sm + SMEM_H2);
    uint2* xb = (uint2*)(sm + SMEM_XB);
    float* csum = (float*)(sm + SMEM_CSUM);

    const int t = threadIdx.x;
    const int rowbase = blockIdx.x << 2;

    // Prefetch stage-B metadata (in flight across stage A + barrier).
    uint32_t pI[8];
    uint4 pC[8];
#pragma unroll
    for (int k = 0; k < 8; ++k) {
        int g = t + (k << 10);
        pI[k] = idxp[g];
        pC[k] = coefb[g];
    }

    // Stage A: 4 rows of x -> fp16, row-interleaved into xb.
    {
        const float* xp = x + (size_t)rowbase * D0 + t;
        float v0 = xp[0];
        float v1 = xp[D0];
        float v2 = xp[2 * D0];
        float v3 = xp[3 * D0];
        uint2 v;
        v.x = __builtin_bit_cast(uint32_t, __floats2half2_rn(v0, v1));
        v.y = __builtin_bit_cast(uint32_t, __floats2half2_rn(v2, v3));
        xb[t] = v;
    }
    if (t < 40) csum[t] = 0.f;
    __syncthreads();

    // Stage B: layer 1 (gather from xb; packed offsets need +SMEM_XB base).
#pragma unroll
    for (int k = 0; k < 8; ++k) {
        int g = t + (k << 10);
        uint32_t ip = pI[k];
        uint2 av = *(const uint2*)(sm + SMEM_XB + (ip & 0xffffu));
        uint2 bv = *(const uint2*)(sm + SMEM_XB + (ip >> 16));
        h1[g] = gate4(av, bv, pC[k]);
    }
    // Prefetch stage-C metadata before the barrier.
#pragma unroll
    for (int k = 0; k < 8; ++k) {
        int g = D1 + t + (k << 10);
        pI[k] = idxp[g];
        pC[k] = coefb[g];
    }
    __syncthreads();

    // Stage C: layer 2 (gather from h1 at LDS base 0 -> zero-add addressing).
#pragma unroll
    for (int k = 0; k < 8; ++k) {
        int g = t + (k << 10);
        uint32_t ip = pI[k];
        uint2 av = *(const uint2*)(sm + (ip & 0xffffu));
        uint2 bv = *(const uint2*)(sm + (ip >> 16));
        h2[g] = gate4(av, bv, pC[k]);
    }
    __syncthreads();

    // Stage D: layer 3 + grouped sum. Each wave owns 640 contiguous gates
    // (spans <=2 classes; 64-gate chunks never straddle a class boundary).
    {
        const int wv = t >> 6, lane = t & 63;
        const int gbase = wv * 640;
        const int cA = gbase >> 10;
        const int bnd = (cA + 1) << 10;
        float s0[4] = {0.f, 0.f, 0.f, 0.f};
        float s1[4] = {0.f, 0.f, 0.f, 0.f};
#pragma unroll
        for (int j = 0; j < 10; ++j) {
            int gc = gbase + (j << 6);
            int g = D1 + D2 + gc + lane;
            uint32_t ip = idxp[g];
            uint4 cf = coefb[g];
            uint2 av = *(const uint2*)(sm + SMEM_H2 + (ip & 0xffffu));
            uint2 bv = *(const uint2*)(sm + SMEM_H2 + (ip >> 16));
            uint2 hv = gate4(av, bv, cf);
            __half2 h01 = __builtin_bit_cast(__half2, hv.x);
            __half2 h23 = __builtin_bit_cast(__half2, hv.y);
            float f0 = __low2float(h01), f1 = __high2float(h01);
            float f2 = __low2float(h23), f3 = __high2float(h23);
            if (gc < bnd) {
                s0[0] += f0; s0[1] += f1; s0[2] += f2; s0[3] += f3;
            } else {
                s1[0] += f0; s1[1] += f1; s1[2] += f2; s1[3] += f3;
            }
        }
        // Wave butterfly reduction (64 lanes).
#pragma unroll
        for (int m = 1; m < 64; m <<= 1) {
#pragma unroll
            for (int r = 0; r < 4; ++r) {
                s0[r] += __shfl_xor(s0[r], m, 64);
                s1[r] += __shfl_xor(s1[r], m, 64);
            }
        }
        if (lane == 0) {
#pragma unroll
            for (int r = 0; r < 4; ++r) atomicAdd(&csum[cA * 4 + r], s0[r]);
            if (gbase + 640 > bnd) {
#pragma unroll
                for (int r = 0; r < 4; ++r) atomicAdd(&csum[(cA + 1) * 4 + r], s1[r]);
            }
        }
    }
    __syncthreads();

    if (t < 40) {
        int c = t >> 2, r = t & 3;
        out[(size_t)(rowbase + r) * 10 + c] = csum[t] * (1.0f / 30.0f);
    }
}

extern "C" void kernel_launch(void* const* d_in, const int* in_sizes, int n_in,
                              void* d_out, int out_size, void* d_ws, size_t ws_size,
                              hipStream_t stream) {
    const float* x = (const float*)d_in[0];
    const float* w1 = (const float*)d_in[1];
    const float* w2 = (const float*)d_in[2];
    const float* w3 = (const float*)d_in[3];
    const int* ia1 = (const int*)d_in[4];
    const int* ib1 = (const int*)d_in[5];
    const int* ia2 = (const int*)d_in[6];
    const int* ib2 = (const int*)d_in[7];
    const int* ia3 = (const int*)d_in[8];
    const int* ib3 = (const int*)d_in[9];
    float* out = (float*)d_out;

    uint4* coefb = (uint4*)d_ws;                                          // 26624 * 16 B
    uint32_t* idxp = (uint32_t*)((char*)d_ws + (size_t)NGATES * 16);      // 26624 * 4 B

    // >64KB dynamic LDS needs the opt-in (host-side call; graph-capture safe).
    hipFuncSetAttribute(reinterpret_cast<const void*>(fused_kernel),
                        hipFuncAttributeMaxDynamicSharedMemorySize, SMEM_BYTES);

    prep_kernel<<<NGATES / 64, 64, 0, stream>>>(
        w1, w2, w3, ia1, ib1, ia2, ib2, ia3, ib3, coefb, idxp);
    fused_kernel<<<B_ROWS / 4, 1024, SMEM_BYTES, stream>>>(x, coefb, idxp, out);
}